// Round 1
// baseline (1166.499 us; speedup 1.0000x reference)
//
#include <hip/hip_runtime.h>
#include <hip/hip_bf16.h>
#include <math.h>

// Problem dims (fixed by the reference)
namespace {
constexpr int Bb   = 4;
constexpr int SEQ  = 1024;
constexpr int DIM  = 768;   // D_EMB == E_DIM
constexpr int NE   = 128;   // entities
constexpr int NH   = 12;    // heads
constexpr int KD   = 64;    // key dim

__device__ __forceinline__ float fast_tanhf(float x) {
  float ax = fabsf(x);
  float t  = __expf(-2.0f * ax);
  float r  = (1.0f - t) / (1.0f + t);
  return copysignf(r, x);
}

__device__ __forceinline__ float geluf(float x) {
  // jax.nn.gelu(approximate=True): 0.5*x*(1+tanh(sqrt(2/pi)*(x+0.044715x^3)))
  float u = 0.7978845608028654f * (x + 0.044715f * x * x * x);
  return 0.5f * x * (1.0f + fast_tanhf(u));
}

__device__ __forceinline__ float sigmoidf_(float x) {
  return 1.0f / (1.0f + __expf(-x));
}

// ---------------------------------------------------------------- pos add
__global__ __launch_bounds__(256) void posadd_kernel(
    const float* __restrict__ emb, const float* __restrict__ pos,
    float* __restrict__ x) {
  int i = blockIdx.x * 256 + threadIdx.x;      // float4 index; total 786432
  const int perB = SEQ * DIM / 4;              // 196608
  int pi = i - (i / perB) * perB;
  float4 e4 = ((const float4*)emb)[i];
  float4 p4 = ((const float4*)pos)[pi];
  e4.x += p4.x; e4.y += p4.y; e4.z += p4.z; e4.w += p4.w;
  ((float4*)x)[i] = e4;
}

// ---------------------------------------------------------------- context mean
__global__ __launch_bounds__(256) void ctxmean_kernel(
    const float* __restrict__ x, float* __restrict__ ctxv) {
  int b = blockIdx.x / 12, chunk = blockIdx.x % 12;
  int lane = threadIdx.x & 63, sg = threadIdx.x >> 6;
  int d = chunk * 64 + lane;
  float acc = 0.f;
  const float* xb = x + ((size_t)b * SEQ + sg) * DIM + d;
  for (int s = sg; s < SEQ; s += 4) { acc += *xb; xb += 4 * DIM; }
  __shared__ float red[4][64];
  red[sg][lane] = acc;
  __syncthreads();
  if (threadIdx.x < 64) {
    float t = red[0][threadIdx.x] + red[1][threadIdx.x] +
              red[2][threadIdx.x] + red[3][threadIdx.x];
    ctxv[b * DIM + chunk * 64 + threadIdx.x] = t * (1.0f / 1024.0f);
  }
}

// ---------------------------------------------------------------- GEMM  C[MxN=768] = A[Mx768] @ W[768x768] (+bias)
__global__ __launch_bounds__(256) void gemm768_kernel(
    const float* __restrict__ A, const float* __restrict__ W,
    const float* __restrict__ bias, float* __restrict__ C, int M) {
  __shared__ __align__(16) float sA[16][68];   // [kk][m], pad to 68 (16B-mult stride)
  __shared__ __align__(16) float sB[16][68];   // [kk][n]
  const int bm = blockIdx.x * 64;
  const int bn = blockIdx.y * 64;
  const int tid = threadIdx.x;
  const int tm = (tid >> 4) * 4;
  const int tn = (tid & 15) * 4;
  const int lm = tid >> 2, lkq = (tid & 3) * 4;     // A loader: (m, k-quad)
  const int lkk = tid >> 4, lnq = (tid & 15) * 4;   // W loader: (kk, n-quad)
  float acc[4][4] = {};
  for (int k0 = 0; k0 < 768; k0 += 16) {
    float4 av = make_float4(0.f, 0.f, 0.f, 0.f);
    if (bm + lm < M) av = *(const float4*)&A[(size_t)(bm + lm) * 768 + k0 + lkq];
    sA[lkq + 0][lm] = av.x; sA[lkq + 1][lm] = av.y;
    sA[lkq + 2][lm] = av.z; sA[lkq + 3][lm] = av.w;
    float4 wv = *(const float4*)&W[(size_t)(k0 + lkk) * 768 + bn + lnq];
    *(float4*)&sB[lkk][lnq] = wv;
    __syncthreads();
#pragma unroll
    for (int kk = 0; kk < 16; ++kk) {
      float4 a = *(const float4*)&sA[kk][tm];
      float4 w = *(const float4*)&sB[kk][tn];
      acc[0][0] += a.x * w.x; acc[0][1] += a.x * w.y; acc[0][2] += a.x * w.z; acc[0][3] += a.x * w.w;
      acc[1][0] += a.y * w.x; acc[1][1] += a.y * w.y; acc[1][2] += a.y * w.z; acc[1][3] += a.y * w.w;
      acc[2][0] += a.z * w.x; acc[2][1] += a.z * w.y; acc[2][2] += a.z * w.z; acc[2][3] += a.z * w.w;
      acc[3][0] += a.w * w.x; acc[3][1] += a.w * w.y; acc[3][2] += a.w * w.z; acc[3][3] += a.w * w.w;
    }
    __syncthreads();
  }
#pragma unroll
  for (int i = 0; i < 4; ++i) {
    int row = bm + tm + i;
    if (row < M) {
#pragma unroll
      for (int j = 0; j < 4; ++j) {
        float o = acc[i][j];
        if (bias) o += bias[bn + tn + j];
        C[(size_t)row * 768 + bn + tn + j] = o;
      }
    }
  }
}

// ---------------------------------------------------------------- attention per (b,h,n) row
__global__ __launch_bounds__(256) void attn_kernel(
    const float* __restrict__ q, const float* __restrict__ k,
    const float* __restrict__ v, float* __restrict__ ctx,
    float* __restrict__ invsum) {
  const int bid = blockIdx.x;            // b*H*N + h*N + n
  const int n = bid & 127;
  const int bh = bid >> 7;
  const int h = bh % 12, b = bh / 12;
  const int tid = threadIdx.x;

  __shared__ float p[1024];
  __shared__ float qs[64];
  __shared__ float wred[4], wsum[4];
  __shared__ float cred[4][64];

  if (tid < 64) qs[tid] = q[n * 768 + h * 64 + tid];
  __syncthreads();

  // scores: 16 lanes per score (each lane a float4 chunk of the 64-dot)
  const int sub = tid & 15, sg = tid >> 4;
  float4 qv = *(const float4*)&qs[sub * 4];
  const float* kb = k + (size_t)b * SEQ * 768 + h * 64;
  for (int s0 = 0; s0 < SEQ; s0 += 16) {
    int s = s0 + sg;
    float4 kv = *(const float4*)&kb[(size_t)s * 768 + sub * 4];
    float d = qv.x * kv.x + qv.y * kv.y + qv.z * kv.z + qv.w * kv.w;
    d += __shfl_xor(d, 1); d += __shfl_xor(d, 2);
    d += __shfl_xor(d, 4); d += __shfl_xor(d, 8);
    if (sub == 0) p[s] = d * 0.125f;   // 1/sqrt(64)
  }
  __syncthreads();

  // softmax (stable)
  float m = -INFINITY;
  for (int i = tid; i < SEQ; i += 256) m = fmaxf(m, p[i]);
  for (int off = 32; off; off >>= 1) m = fmaxf(m, __shfl_xor(m, off));
  if ((tid & 63) == 0) wred[tid >> 6] = m;
  __syncthreads();
  m = fmaxf(fmaxf(wred[0], wred[1]), fmaxf(wred[2], wred[3]));

  float sum = 0.f;
  for (int i = tid; i < SEQ; i += 256) {
    float e = __expf(p[i] - m);
    p[i] = e;
    sum += e;
  }
  for (int off = 32; off; off >>= 1) sum += __shfl_xor(sum, off);
  if ((tid & 63) == 0) wsum[tid >> 6] = sum;
  __syncthreads();
  float Ssum = wsum[0] + wsum[1] + wsum[2] + wsum[3];
  float inv = 1.0f / Ssum;               // == max_s attn (since exp(0)=1 at the max)
  if (tid == 0) invsum[bid] = inv;

  // ctx[b,n,h,:] = (sum_s p[s] * v[b,s,h,:]) * inv
  const int kk = tid & 63, g = tid >> 6;
  const float* vb = v + (size_t)b * SEQ * 768 + h * 64 + kk;
  float acc = 0.f;
  for (int s = g; s < SEQ; s += 4) acc += p[s] * vb[(size_t)s * 768];
  cred[g][kk] = acc;
  __syncthreads();
  if (tid < 64) {
    float c = (cred[0][tid] + cred[1][tid] + cred[2][tid] + cred[3][tid]) * inv;
    ctx[((size_t)(b * NE + n)) * 768 + h * 64 + tid] = c;
  }
}

// ---------------------------------------------------------------- entity mask
__global__ void mask_kernel(const float* __restrict__ invsum,
                            float* __restrict__ mask_out) {
  int t = threadIdx.x;                   // 512 = B*N
  int b = t >> 7, n = t & 127;
  float a = 0.f;
  for (int h = 0; h < 12; ++h) a = fmaxf(a, invsum[(b * 12 + h) * 128 + n]);
  mask_out[t] = (a > 0.001f) ? 1.0f : 0.0f;
}

// ---------------------------------------------------------------- masked entities out
__global__ __launch_bounds__(256) void entmask_kernel(
    const float* __restrict__ ent, const float* __restrict__ mask,
    float* __restrict__ out) {
  int bi = blockIdx.x;                   // b*128+i
  float m = mask[bi];
  for (int e = threadIdx.x; e < 768; e += 256)
    out[(size_t)bi * 768 + e] = ent[(size_t)bi * 768 + e] * m;
}

// ---------------------------------------------------------------- fused edge refinement + gate + mask
__global__ __launch_bounds__(256) void refine_kernel(
    const float* __restrict__ A1, const float* __restrict__ B1,
    const float* __restrict__ C1, const float* __restrict__ w1g,
    const float* __restrict__ W2, const float* __restrict__ b2,
    const float* __restrict__ Ag, const float* __restrict__ Bg,
    const float* __restrict__ Wg2, const float* __restrict__ bg2,
    const float* __restrict__ graph_init, const float* __restrict__ mask,
    float* __restrict__ graph_out) {
  const int bi = blockIdx.x;             // b*128 + i
  const int b = bi >> 7;
  const int lane = threadIdx.x & 63, wv = threadIdx.x >> 6;

  float base[12], w1gr[12], w2r[12], agr[12], wg2r[12];
#pragma unroll
  for (int r = 0; r < 12; ++r) {
    int e = r * 64 + lane;
    base[r] = A1[(size_t)bi * 768 + e] + C1[b * 768 + e];  // C1 includes b1
    w1gr[r] = w1g[e];
    w2r[r]  = W2[e];
    agr[r]  = Ag[(size_t)bi * 768 + e];                    // Ag includes bg1
    wg2r[r] = Wg2[e];
  }
  const float b2s = b2[0], bg2s = bg2[0];
  const float mi = mask[bi];

  for (int j = wv; j < 128; j += 4) {
    float g = graph_init[(size_t)bi * 128 + j] * 1.6f - 0.8f;
    const float* B1j = &B1[((size_t)(b * NE + j)) * 768 + lane];
    const float* Bgj = &Bg[((size_t)(b * NE + j)) * 768 + lane];
    float pre[12], gpre[12];
#pragma unroll
    for (int r = 0; r < 12; ++r) {
      pre[r]  = base[r] + B1j[r * 64];
      gpre[r] = agr[r] + Bgj[r * 64];
    }
#pragma unroll
    for (int st = 0; st < 3; ++st) {
      float acc = 0.f;
#pragma unroll
      for (int r = 0; r < 12; ++r) {
        float hx = pre[r] + g * w1gr[r];
        acc += geluf(hx) * w2r[r];
      }
      acc += __shfl_xor(acc, 1);  acc += __shfl_xor(acc, 2);
      acc += __shfl_xor(acc, 4);  acc += __shfl_xor(acc, 8);
      acc += __shfl_xor(acc, 16); acc += __shfl_xor(acc, 32);
      g += fast_tanhf(acc + b2s);
    }
    float gacc = 0.f;
#pragma unroll
    for (int r = 0; r < 12; ++r) gacc += geluf(gpre[r]) * wg2r[r];
    gacc += __shfl_xor(gacc, 1);  gacc += __shfl_xor(gacc, 2);
    gacc += __shfl_xor(gacc, 4);  gacc += __shfl_xor(gacc, 8);
    gacc += __shfl_xor(gacc, 16); gacc += __shfl_xor(gacc, 32);
    float gate = sigmoidf_(gacc + bg2s);
    if (lane == 0)
      graph_out[(size_t)bi * 128 + j] = g * gate * mi * mask[b * NE + j];
  }
}

}  // namespace

extern "C" void kernel_launch(void* const* d_in, const int* in_sizes, int n_in,
                              void* d_out, int out_size, void* d_ws, size_t ws_size,
                              hipStream_t stream) {
  const float* emb  = (const float*)d_in[0];
  const float* ginit= (const float*)d_in[1];
  const float* lib  = (const float*)d_in[2];
  const float* pos  = (const float*)d_in[3];
  const float* Wq   = (const float*)d_in[4];
  const float* bq   = (const float*)d_in[5];
  const float* Wk   = (const float*)d_in[6];
  const float* bk   = (const float*)d_in[7];
  const float* Wv   = (const float*)d_in[8];
  const float* bv   = (const float*)d_in[9];
  const float* Wo   = (const float*)d_in[10];
  const float* bo   = (const float*)d_in[11];
  const float* W1   = (const float*)d_in[12];
  const float* b1   = (const float*)d_in[13];
  const float* W2   = (const float*)d_in[14];
  const float* b2   = (const float*)d_in[15];
  const float* Wg1  = (const float*)d_in[16];
  const float* bg1  = (const float*)d_in[17];
  const float* Wg2  = (const float*)d_in[18];
  const float* bg2  = (const float*)d_in[19];

  float* ws = (float*)d_ws;
  float* k_   = ws + 0;                 // 3,145,728
  float* v_   = ws + 3145728;           // 3,145,728
  float* x_   = ws + 6291456;           // 3,145,728 (dead after K/V/context)
  float* A1   = ws + 6291456;           // reuse x space
  float* B1   = ws + 6684672;
  float* Ag   = ws + 7077888;
  float* Bg   = ws + 7471104;
  float* q_   = ws + 9437184;           // 98,304
  float* ctx_ = ws + 9535488;           // 393,216
  float* ent_ = ws + 9928704;           // 393,216
  float* ctxv = ws + 10321920;          // 3,072
  float* C1   = ws + 10324992;          // 3,072
  float* invs = ws + 10328064;          // 6,144

  float* out_ent   = (float*)d_out;           // 393,216
  float* out_graph = out_ent + 393216;        // 65,536
  float* out_mask  = out_ent + 458752;        // 512

  // 1. x = emb + pos
  posadd_kernel<<<3072, 256, 0, stream>>>(emb, pos, x_);
  // 2. context = mean_s x
  ctxmean_kernel<<<48, 256, 0, stream>>>(x_, ctxv);
  // 3. q = lib @ Wq + bq
  gemm768_kernel<<<dim3(2, 12), 256, 0, stream>>>(lib, Wq, bq, q_, 128);
  // 4/5. k, v = x @ Wk/Wv + bk/bv  (layout (B,S,H*K) row-major)
  gemm768_kernel<<<dim3(64, 12), 256, 0, stream>>>(x_, Wk, bk, k_, 4096);
  gemm768_kernel<<<dim3(64, 12), 256, 0, stream>>>(x_, Wv, bv, v_, 4096);
  // 6. attention -> ctx (B,N,H*K), invsum (B,H,N)
  attn_kernel<<<6144, 256, 0, stream>>>(q_, k_, v_, ctx_, invs);
  // 7. entity mask
  mask_kernel<<<1, 512, 0, stream>>>(invs, out_mask);
  // 8. entities = ctx @ Wo + bo
  gemm768_kernel<<<dim3(8, 12), 256, 0, stream>>>(ctx_, Wo, bo, ent_, 512);
  // 9. masked entities out
  entmask_kernel<<<512, 256, 0, stream>>>(ent_, out_mask, out_ent);
  // 10-13. per-entity projections for edge MLPs
  gemm768_kernel<<<dim3(8, 12), 256, 0, stream>>>(ent_, W1, nullptr, A1, 512);
  gemm768_kernel<<<dim3(8, 12), 256, 0, stream>>>(ent_, W1 + 589824, nullptr, B1, 512);
  gemm768_kernel<<<dim3(8, 12), 256, 0, stream>>>(ent_, Wg1, bg1, Ag, 512);
  gemm768_kernel<<<dim3(8, 12), 256, 0, stream>>>(ent_, Wg1 + 589824, nullptr, Bg, 512);
  // 14. C1 = context @ W1d + b1   (W1 row 1536 = graph weight; 1537.. = ctx rows)
  gemm768_kernel<<<dim3(1, 12), 256, 0, stream>>>(ctxv, W1 + 1537 * 768, b1, C1, 4);
  // 15. fused edge refinement (3 steps) + gate + entity masking
  refine_kernel<<<512, 256, 0, stream>>>(A1, B1, C1, W1 + 1536 * 768, W2, b2,
                                         Ag, Bg, Wg2, bg2, ginit, out_mask,
                                         out_graph);
}

// Round 2
// 819.895 us; speedup vs baseline: 1.4227x; 1.4227x over previous
//
#include <hip/hip_runtime.h>
#include <hip/hip_bf16.h>
#include <math.h>

namespace {
constexpr int SEQ  = 1024;
constexpr int NE   = 128;

__device__ __forceinline__ float fast_tanhf(float x) {
  float ax = fabsf(x);
  float t  = __expf(-2.0f * ax);
  float r  = (1.0f - t) / (1.0f + t);
  return copysignf(r, x);
}

__device__ __forceinline__ float geluf(float x) {
  float u = 0.7978845608028654f * (x + 0.044715f * x * x * x);
  return 0.5f * x * (1.0f + fast_tanhf(u));
}

__device__ __forceinline__ float sigmoidf_(float x) {
  return 1.0f / (1.0f + __expf(-x));
}

// ---------------------------------------------------------------- pos add
__global__ __launch_bounds__(256) void posadd_kernel(
    const float* __restrict__ emb, const float* __restrict__ pos,
    float* __restrict__ x) {
  int i = blockIdx.x * 256 + threadIdx.x;      // float4 index; total 786432
  const int perB = SEQ * 768 / 4;              // 196608
  int pi = i - (i / perB) * perB;
  float4 e4 = ((const float4*)emb)[i];
  float4 p4 = ((const float4*)pos)[pi];
  e4.x += p4.x; e4.y += p4.y; e4.z += p4.z; e4.w += p4.w;
  ((float4*)x)[i] = e4;
}

// ---------------------------------------------------------------- context mean
__global__ __launch_bounds__(256) void ctxmean_kernel(
    const float* __restrict__ x, float* __restrict__ ctxv) {
  int b = blockIdx.x / 12, chunk = blockIdx.x % 12;
  int lane = threadIdx.x & 63, sg = threadIdx.x >> 6;
  int d = chunk * 64 + lane;
  float acc = 0.f;
  const float* xb = x + ((size_t)b * SEQ + sg) * 768 + d;
  for (int s = sg; s < SEQ; s += 4) { acc += *xb; xb += 4 * 768; }
  __shared__ float red[4][64];
  red[sg][lane] = acc;
  __syncthreads();
  if (threadIdx.x < 64) {
    float t = red[0][threadIdx.x] + red[1][threadIdx.x] +
              red[2][threadIdx.x] + red[3][threadIdx.x];
    ctxv[b * 768 + chunk * 64 + threadIdx.x] = t * (1.0f / 1024.0f);
  }
}

// ---------------------------------------------------------------- small GEMM  C[Mx768] = A[Mx768] @ W[768x768] (+bias)
__global__ __launch_bounds__(256) void gemm768_kernel(
    const float* __restrict__ A, const float* __restrict__ W,
    const float* __restrict__ bias, float* __restrict__ C, int M) {
  __shared__ __align__(16) float sA[16][68];
  __shared__ __align__(16) float sB[16][68];
  const int bm = blockIdx.x * 64;
  const int bn = blockIdx.y * 64;
  const int tid = threadIdx.x;
  const int tm = (tid >> 4) * 4;
  const int tn = (tid & 15) * 4;
  const int lm = tid >> 2, lkq = (tid & 3) * 4;
  const int lkk = tid >> 4, lnq = (tid & 15) * 4;
  float acc[4][4] = {};
  for (int k0 = 0; k0 < 768; k0 += 16) {
    float4 av = make_float4(0.f, 0.f, 0.f, 0.f);
    if (bm + lm < M) av = *(const float4*)&A[(size_t)(bm + lm) * 768 + k0 + lkq];
    float4 wv = *(const float4*)&W[(size_t)(k0 + lkk) * 768 + bn + lnq];
    __syncthreads();
    sA[lkq + 0][lm] = av.x; sA[lkq + 1][lm] = av.y;
    sA[lkq + 2][lm] = av.z; sA[lkq + 3][lm] = av.w;
    *(float4*)&sB[lkk][lnq] = wv;
    __syncthreads();
#pragma unroll
    for (int kk = 0; kk < 16; ++kk) {
      float4 a = *(const float4*)&sA[kk][tm];
      float4 w = *(const float4*)&sB[kk][tn];
      acc[0][0] += a.x * w.x; acc[0][1] += a.x * w.y; acc[0][2] += a.x * w.z; acc[0][3] += a.x * w.w;
      acc[1][0] += a.y * w.x; acc[1][1] += a.y * w.y; acc[1][2] += a.y * w.z; acc[1][3] += a.y * w.w;
      acc[2][0] += a.z * w.x; acc[2][1] += a.z * w.y; acc[2][2] += a.z * w.z; acc[2][3] += a.z * w.w;
      acc[3][0] += a.w * w.x; acc[3][1] += a.w * w.y; acc[3][2] += a.w * w.z; acc[3][3] += a.w * w.w;
    }
  }
#pragma unroll
  for (int i = 0; i < 4; ++i) {
    int row = bm + tm + i;
    if (row < M) {
#pragma unroll
      for (int j = 0; j < 4; ++j) {
        float o = acc[i][j];
        if (bias) o += bias[bn + tn + j];
        C[(size_t)row * 768 + bn + tn + j] = o;
      }
    }
  }
}

// ---------------------------------------------------------------- 4-way fused projection GEMM (shared A, M=512)
struct ProjParams {
  const float* W[4];
  const float* bias[4];
  float* C[4];
};

__global__ __launch_bounds__(256) void gemm768x4_kernel(
    const float* __restrict__ A, ProjParams pp) {
  __shared__ __align__(16) float sA[16][68];
  __shared__ __align__(16) float sB[16][68];
  const int sel = blockIdx.y / 12;
  const float* W = pp.W[sel];
  const float* bias = pp.bias[sel];
  float* C = pp.C[sel];
  const int bm = blockIdx.x * 64;
  const int bn = (blockIdx.y % 12) * 64;
  const int tid = threadIdx.x;
  const int tm = (tid >> 4) * 4;
  const int tn = (tid & 15) * 4;
  const int lm = tid >> 2, lkq = (tid & 3) * 4;
  const int lkk = tid >> 4, lnq = (tid & 15) * 4;
  float acc[4][4] = {};
  for (int k0 = 0; k0 < 768; k0 += 16) {
    float4 av = *(const float4*)&A[(size_t)(bm + lm) * 768 + k0 + lkq];
    float4 wv = *(const float4*)&W[(size_t)(k0 + lkk) * 768 + bn + lnq];
    __syncthreads();
    sA[lkq + 0][lm] = av.x; sA[lkq + 1][lm] = av.y;
    sA[lkq + 2][lm] = av.z; sA[lkq + 3][lm] = av.w;
    *(float4*)&sB[lkk][lnq] = wv;
    __syncthreads();
#pragma unroll
    for (int kk = 0; kk < 16; ++kk) {
      float4 a = *(const float4*)&sA[kk][tm];
      float4 w = *(const float4*)&sB[kk][tn];
      acc[0][0] += a.x * w.x; acc[0][1] += a.x * w.y; acc[0][2] += a.x * w.z; acc[0][3] += a.x * w.w;
      acc[1][0] += a.y * w.x; acc[1][1] += a.y * w.y; acc[1][2] += a.y * w.z; acc[1][3] += a.y * w.w;
      acc[2][0] += a.z * w.x; acc[2][1] += a.z * w.y; acc[2][2] += a.z * w.z; acc[2][3] += a.z * w.w;
      acc[3][0] += a.w * w.x; acc[3][1] += a.w * w.y; acc[3][2] += a.w * w.z; acc[3][3] += a.w * w.w;
    }
  }
#pragma unroll
  for (int i = 0; i < 4; ++i) {
    int row = bm + tm + i;
#pragma unroll
    for (int j = 0; j < 4; ++j) {
      float o = acc[i][j];
      if (bias) o += bias[bn + tn + j];
      C[(size_t)row * 768 + bn + tn + j] = o;
    }
  }
}

// ---------------------------------------------------------------- fused K+V GEMM, 128x128 tile, 8x8 micro, transposed (B,H,S,64) output
__global__ __launch_bounds__(256) void kv_gemm_kernel(
    const float* __restrict__ A,
    const float* __restrict__ Wk, const float* __restrict__ bk,
    const float* __restrict__ Wv, const float* __restrict__ bv,
    float* __restrict__ k2, float* __restrict__ v2) {
  __shared__ __align__(16) float sA[16][132];
  __shared__ __align__(16) float sB[16][132];
  const int bm = blockIdx.x * 128;
  const bool isV = blockIdx.y >= 6;
  const int bn = (blockIdx.y % 6) * 128;
  const float* W = isV ? Wv : Wk;
  const float* bias = isV ? bv : bk;
  float* out = isV ? v2 : k2;
  const int t = threadIdx.x;
  const int ty = t >> 4, tx = t & 15;
  const int ar = t >> 1, akq = (t & 1) * 8;
  const int bkk = t >> 4, bc = (t & 15) * 8;

  float acc[8][8] = {};
  for (int k0 = 0; k0 < 768; k0 += 16) {
    float4 a0 = *(const float4*)&A[(size_t)(bm + ar) * 768 + k0 + akq];
    float4 a1 = *(const float4*)&A[(size_t)(bm + ar) * 768 + k0 + akq + 4];
    float4 b0 = *(const float4*)&W[(size_t)(k0 + bkk) * 768 + bn + bc];
    float4 b1 = *(const float4*)&W[(size_t)(k0 + bkk) * 768 + bn + bc + 4];
    __syncthreads();
    sA[akq + 0][ar] = a0.x; sA[akq + 1][ar] = a0.y;
    sA[akq + 2][ar] = a0.z; sA[akq + 3][ar] = a0.w;
    sA[akq + 4][ar] = a1.x; sA[akq + 5][ar] = a1.y;
    sA[akq + 6][ar] = a1.z; sA[akq + 7][ar] = a1.w;
    *(float4*)&sB[bkk][bc] = b0;
    *(float4*)&sB[bkk][bc + 4] = b1;
    __syncthreads();
#pragma unroll
    for (int kk = 0; kk < 16; ++kk) {
      float4 x0 = *(const float4*)&sA[kk][ty * 4];
      float4 x1 = *(const float4*)&sA[kk][64 + ty * 4];
      float4 y0 = *(const float4*)&sB[kk][tx * 4];
      float4 y1 = *(const float4*)&sB[kk][64 + tx * 4];
      float xa[8] = {x0.x, x0.y, x0.z, x0.w, x1.x, x1.y, x1.z, x1.w};
      float yb[8] = {y0.x, y0.y, y0.z, y0.w, y1.x, y1.y, y1.z, y1.w};
#pragma unroll
      for (int i = 0; i < 8; ++i)
#pragma unroll
        for (int j = 0; j < 8; ++j)
          acc[i][j] += xa[i] * yb[j];
    }
  }

  const int bidx = bm >> 10;            // batch
  const int s_base = bm & 1023;
  const int h0 = bn >> 6;
  float bs0[4], bs1[4];
#pragma unroll
  for (int j = 0; j < 4; ++j) {
    bs0[j] = bias[bn + tx * 4 + j];
    bs1[j] = bias[bn + 64 + tx * 4 + j];
  }
#pragma unroll
  for (int i = 0; i < 8; ++i) {
    int s = s_base + ((i < 4) ? (ty * 4 + i) : (64 + ty * 4 + (i - 4)));
    float4 o0 = make_float4(acc[i][0] + bs0[0], acc[i][1] + bs0[1],
                            acc[i][2] + bs0[2], acc[i][3] + bs0[3]);
    float4 o1 = make_float4(acc[i][4] + bs1[0], acc[i][5] + bs1[1],
                            acc[i][6] + bs1[2], acc[i][7] + bs1[3]);
    *(float4*)&out[(((size_t)(bidx * 12 + h0)) * 1024 + s) * 64 + tx * 4] = o0;
    *(float4*)&out[(((size_t)(bidx * 12 + h0 + 1)) * 1024 + s) * 64 + tx * 4] = o1;
  }
}

// ---------------------------------------------------------------- flash-style attention, 16 queries/block, (B,H,S,64) K/V
__global__ __launch_bounds__(256) void attn2_kernel(
    const float* __restrict__ q, const float* __restrict__ k2,
    const float* __restrict__ v2, float* __restrict__ ctx,
    float* __restrict__ invsum) {
  __shared__ float p[16][1028];
  __shared__ float4 sK[128 * 16];         // swizzled: [s][dq ^ (s&7)]
  __shared__ float4 sQ[16][16];
  __shared__ float linv[16];
  __shared__ float4 part[4][4][4][16];    // [sq][nq][i][dq]

  const int bid = blockIdx.x;             // 384 = 4 * 12 * 8
  const int b = bid / 96;
  const int rem = bid % 96;
  const int h = rem >> 3;
  const int ng = rem & 7;
  const int t = threadIdx.x;

  {  // stage Q, fold 1/sqrt(64)
    int nn = t >> 4, dq = t & 15;
    float4 qv = *(const float4*)&q[(size_t)(ng * 16 + nn) * 768 + h * 64 + dq * 4];
    qv.x *= 0.125f; qv.y *= 0.125f; qv.z *= 0.125f; qv.w *= 0.125f;
    sQ[nn][dq] = qv;
  }
  const float4* kbh = (const float4*)(k2 + ((size_t)(b * 12 + h)) * 1024 * 64);
  const float4* vbh = (const float4*)(v2 + ((size_t)(b * 12 + h)) * 1024 * 64);

  const int npair = t >> 5;               // 0..7
  const int g = t & 31;
  const int n0 = npair * 2, n1 = n0 + 1;

  // ---- QK^T into p ----
  for (int c = 0; c < 8; ++c) {
    __syncthreads();
#pragma unroll
    for (int w = 0; w < 8; ++w) {
      int fi = w * 256 + t;
      int sl = fi >> 4, dq = fi & 15;
      sK[sl * 16 + (dq ^ (sl & 7))] = kbh[c * 2048 + fi];
    }
    __syncthreads();
    float4 a0[4] = {}, a1[4] = {};
#pragma unroll
    for (int d0 = 0; d0 < 16; ++d0) {
      float4 q0 = sQ[n0][d0];
      float4 q1 = sQ[n1][d0];
      int slot = d0 ^ (g & 7);
#pragma unroll
      for (int u = 0; u < 4; ++u) {
        float4 kv = sK[(g + 32 * u) * 16 + slot];
        a0[u].x += q0.x * kv.x; a0[u].y += q0.y * kv.y;
        a0[u].z += q0.z * kv.z; a0[u].w += q0.w * kv.w;
        a1[u].x += q1.x * kv.x; a1[u].y += q1.y * kv.y;
        a1[u].z += q1.z * kv.z; a1[u].w += q1.w * kv.w;
      }
    }
#pragma unroll
    for (int u = 0; u < 4; ++u) {
      int s = c * 128 + g + 32 * u;
      p[n0][s] = a0[u].x + a0[u].y + a0[u].z + a0[u].w;
      p[n1][s] = a1[u].x + a1[u].y + a1[u].z + a1[u].w;
    }
  }
  __syncthreads();

  // ---- softmax per row; activity = 1/sum ----
  {
    int n = t >> 4, sub = t & 15;
    float m = -1e30f;
#pragma unroll 8
    for (int u = 0; u < 64; ++u) m = fmaxf(m, p[n][sub + 16 * u]);
    m = fmaxf(m, __shfl_xor(m, 1)); m = fmaxf(m, __shfl_xor(m, 2));
    m = fmaxf(m, __shfl_xor(m, 4)); m = fmaxf(m, __shfl_xor(m, 8));
    float sum = 0.f;
#pragma unroll 8
    for (int u = 0; u < 64; ++u) {
      float e = __expf(p[n][sub + 16 * u] - m);
      p[n][sub + 16 * u] = e;
      sum += e;
    }
    sum += __shfl_xor(sum, 1); sum += __shfl_xor(sum, 2);
    sum += __shfl_xor(sum, 4); sum += __shfl_xor(sum, 8);
    if (sub == 0) {
      float inv = 1.0f / sum;
      linv[n] = inv;
      invsum[(b * 12 + h) * 128 + ng * 16 + n] = inv;
    }
  }

  // ---- PV ----
  const int dq = t & 15, nq = (t >> 4) & 3, sq = t >> 6;
  float4 acc[4] = {};
  for (int c = 0; c < 8; ++c) {
    __syncthreads();
#pragma unroll
    for (int w = 0; w < 8; ++w) {
      int fi = w * 256 + t;
      int sl = fi >> 4, dqq = fi & 15;
      sK[sl * 16 + (dqq ^ (sl & 7))] = vbh[c * 2048 + fi];
    }
    __syncthreads();
#pragma unroll 4
    for (int v = 0; v < 32; ++v) {
      int sl = sq * 32 + v;
      float4 vv = sK[sl * 16 + (dq ^ (sl & 7))];
      int s = c * 128 + sl;
#pragma unroll
      for (int i = 0; i < 4; ++i) {
        float pv = p[nq * 4 + i][s];
        acc[i].x += pv * vv.x; acc[i].y += pv * vv.y;
        acc[i].z += pv * vv.z; acc[i].w += pv * vv.w;
      }
    }
  }
#pragma unroll
  for (int i = 0; i < 4; ++i) part[sq][nq][i][dq] = acc[i];
  __syncthreads();
  {
    int n = t >> 4, dqq = t & 15;
    float4 r0 = part[0][n >> 2][n & 3][dqq];
    float4 r1 = part[1][n >> 2][n & 3][dqq];
    float4 r2 = part[2][n >> 2][n & 3][dqq];
    float4 r3 = part[3][n >> 2][n & 3][dqq];
    float inv = linv[n];
    float4 o;
    o.x = (r0.x + r1.x + r2.x + r3.x) * inv;
    o.y = (r0.y + r1.y + r2.y + r3.y) * inv;
    o.z = (r0.z + r1.z + r2.z + r3.z) * inv;
    o.w = (r0.w + r1.w + r2.w + r3.w) * inv;
    *(float4*)&ctx[(size_t)(b * 128 + ng * 16 + n) * 768 + h * 64 + dqq * 4] = o;
  }
}

// ---------------------------------------------------------------- entity mask
__global__ void mask_kernel(const float* __restrict__ invsum,
                            float* __restrict__ mask_out) {
  int t = threadIdx.x;                   // 512 = B*N
  int b = t >> 7, n = t & 127;
  float a = 0.f;
  for (int h = 0; h < 12; ++h) a = fmaxf(a, invsum[(b * 12 + h) * 128 + n]);
  mask_out[t] = (a > 0.001f) ? 1.0f : 0.0f;
}

// ---------------------------------------------------------------- masked entities out
__global__ __launch_bounds__(256) void entmask_kernel(
    const float* __restrict__ ent, const float* __restrict__ mask,
    float* __restrict__ out) {
  int bi = blockIdx.x;                   // b*128+i
  float m = mask[bi];
  for (int e = threadIdx.x; e < 768; e += 256)
    out[(size_t)bi * 768 + e] = ent[(size_t)bi * 768 + e] * m;
}

// ---------------------------------------------------------------- fused edge refinement + gate + mask
__global__ __launch_bounds__(256) void refine_kernel(
    const float* __restrict__ A1, const float* __restrict__ B1,
    const float* __restrict__ C1, const float* __restrict__ w1g,
    const float* __restrict__ W2, const float* __restrict__ b2,
    const float* __restrict__ Ag, const float* __restrict__ Bg,
    const float* __restrict__ Wg2, const float* __restrict__ bg2,
    const float* __restrict__ graph_init, const float* __restrict__ mask,
    float* __restrict__ graph_out) {
  const int bi = blockIdx.x;             // b*128 + i
  const int b = bi >> 7;
  const int lane = threadIdx.x & 63, wv = threadIdx.x >> 6;

  float base[12], w1gr[12], w2r[12], agr[12], wg2r[12];
#pragma unroll
  for (int r = 0; r < 12; ++r) {
    int e = r * 64 + lane;
    base[r] = A1[(size_t)bi * 768 + e] + C1[b * 768 + e];
    w1gr[r] = w1g[e];
    w2r[r]  = W2[e];
    agr[r]  = Ag[(size_t)bi * 768 + e];
    wg2r[r] = Wg2[e];
  }
  const float b2s = b2[0], bg2s = bg2[0];
  const float mi = mask[bi];

  for (int j = wv; j < 128; j += 4) {
    float g = graph_init[(size_t)bi * 128 + j] * 1.6f - 0.8f;
    const float* B1j = &B1[((size_t)(b * NE + j)) * 768 + lane];
    const float* Bgj = &Bg[((size_t)(b * NE + j)) * 768 + lane];
    float pre[12], gpre[12];
#pragma unroll
    for (int r = 0; r < 12; ++r) {
      pre[r]  = base[r] + B1j[r * 64];
      gpre[r] = agr[r] + Bgj[r * 64];
    }
#pragma unroll
    for (int st = 0; st < 3; ++st) {
      float acc = 0.f;
#pragma unroll
      for (int r = 0; r < 12; ++r) {
        float hx = pre[r] + g * w1gr[r];
        acc += geluf(hx) * w2r[r];
      }
      acc += __shfl_xor(acc, 1);  acc += __shfl_xor(acc, 2);
      acc += __shfl_xor(acc, 4);  acc += __shfl_xor(acc, 8);
      acc += __shfl_xor(acc, 16); acc += __shfl_xor(acc, 32);
      g += fast_tanhf(acc + b2s);
    }
    float gacc = 0.f;
#pragma unroll
    for (int r = 0; r < 12; ++r) gacc += geluf(gpre[r]) * wg2r[r];
    gacc += __shfl_xor(gacc, 1);  gacc += __shfl_xor(gacc, 2);
    gacc += __shfl_xor(gacc, 4);  gacc += __shfl_xor(gacc, 8);
    gacc += __shfl_xor(gacc, 16); gacc += __shfl_xor(gacc, 32);
    float gate = sigmoidf_(gacc + bg2s);
    if (lane == 0)
      graph_out[(size_t)bi * 128 + j] = g * gate * mi * mask[b * NE + j];
  }
}

}  // namespace

extern "C" void kernel_launch(void* const* d_in, const int* in_sizes, int n_in,
                              void* d_out, int out_size, void* d_ws, size_t ws_size,
                              hipStream_t stream) {
  const float* emb  = (const float*)d_in[0];
  const float* ginit= (const float*)d_in[1];
  const float* lib  = (const float*)d_in[2];
  const float* pos  = (const float*)d_in[3];
  const float* Wq   = (const float*)d_in[4];
  const float* bq   = (const float*)d_in[5];
  const float* Wk   = (const float*)d_in[6];
  const float* bk   = (const float*)d_in[7];
  const float* Wv   = (const float*)d_in[8];
  const float* bv   = (const float*)d_in[9];
  const float* Wo   = (const float*)d_in[10];
  const float* bo   = (const float*)d_in[11];
  const float* W1   = (const float*)d_in[12];
  const float* b1   = (const float*)d_in[13];
  const float* W2   = (const float*)d_in[14];
  const float* b2   = (const float*)d_in[15];
  const float* Wg1  = (const float*)d_in[16];
  const float* bg1  = (const float*)d_in[17];
  const float* Wg2  = (const float*)d_in[18];
  const float* bg2  = (const float*)d_in[19];

  float* ws = (float*)d_ws;
  float* k2   = ws + 0;                 // (B,H,S,64)  3,145,728
  float* v2   = ws + 3145728;           // (B,H,S,64)  3,145,728
  float* x_   = ws + 6291456;           // 3,145,728 (dead after K/V/context)
  float* A1   = ws + 6291456;           // reuse x space
  float* B1   = ws + 6684672;
  float* Ag   = ws + 7077888;
  float* Bg   = ws + 7471104;
  float* q_   = ws + 9437184;           // 98,304
  float* ctx_ = ws + 9535488;           // 393,216
  float* ent_ = ws + 9928704;           // 393,216
  float* ctxv = ws + 10321920;          // 3,072
  float* C1   = ws + 10324992;          // 3,072
  float* invs = ws + 10328064;          // 6,144

  float* out_ent   = (float*)d_out;           // 393,216
  float* out_graph = out_ent + 393216;        // 65,536
  float* out_mask  = out_ent + 458752;        // 512

  // 1. x = emb + pos
  posadd_kernel<<<3072, 256, 0, stream>>>(emb, pos, x_);
  // 2. context = mean_s x
  ctxmean_kernel<<<48, 256, 0, stream>>>(x_, ctxv);
  // 3. q = lib @ Wq + bq
  gemm768_kernel<<<dim3(2, 12), 256, 0, stream>>>(lib, Wq, bq, q_, 128);
  // 4. k2/v2 = x @ Wk/Wv + b, transposed to (B,H,S,64)
  kv_gemm_kernel<<<dim3(32, 12), 256, 0, stream>>>(x_, Wk, bk, Wv, bv, k2, v2);
  // 5. attention -> ctx (B,N,H*K), invsum (B,H,N)
  attn2_kernel<<<384, 256, 0, stream>>>(q_, k2, v2, ctx_, invs);
  // 6. entity mask
  mask_kernel<<<1, 512, 0, stream>>>(invs, out_mask);
  // 7. entities = ctx @ Wo + bo
  gemm768_kernel<<<dim3(8, 12), 256, 0, stream>>>(ctx_, Wo, bo, ent_, 512);
  // 8. masked entities out
  entmask_kernel<<<512, 256, 0, stream>>>(ent_, out_mask, out_ent);
  // 9. fused per-entity projections for edge MLPs (A1,B1,Ag,Bg)
  ProjParams pp;
  pp.W[0] = W1;              pp.bias[0] = nullptr; pp.C[0] = A1;
  pp.W[1] = W1 + 589824;     pp.bias[1] = nullptr; pp.C[1] = B1;
  pp.W[2] = Wg1;             pp.bias[2] = bg1;     pp.C[2] = Ag;
  pp.W[3] = Wg1 + 589824;    pp.bias[3] = nullptr; pp.C[3] = Bg;
  gemm768x4_kernel<<<dim3(8, 48), 256, 0, stream>>>(ent_, pp);
  // 10. C1 = context @ W1d + b1
  gemm768_kernel<<<dim3(1, 12), 256, 0, stream>>>(ctxv, W1 + 1537 * 768, b1, C1, 4);
  // 11. fused edge refinement (3 steps) + gate + entity masking
  refine_kernel<<<512, 256, 0, stream>>>(A1, B1, C1, W1 + 1536 * 768, W2, b2,
                                         Ag, Bg, Wg2, bg2, ginit, out_mask,
                                         out_graph);
}

// Round 3
// 713.274 us; speedup vs baseline: 1.6354x; 1.1495x over previous
//
#include <hip/hip_runtime.h>
#include <hip/hip_bf16.h>
#include <math.h>

namespace {
constexpr int SEQ  = 1024;
constexpr int NE   = 128;

__device__ __forceinline__ float rcp_fast(float x) {
  return __builtin_amdgcn_rcpf(x);
}

// gelu(x) = x * sigmoid(2*0.79788456*(x+0.044715x^3)); exp2-form, rcp-based
__device__ __forceinline__ float gelu_fast(float x) {
  float x2 = x * x;
  float t = fmaf(x2, -0.1029443f, -2.3022093f);   // -(2u)*log2(e) / x
  return x * rcp_fast(1.0f + exp2f(x * t));
}

__device__ __forceinline__ float tanh_fast(float x) {
  return 1.0f - 2.0f * rcp_fast(1.0f + exp2f(x * 2.8853901f));
}

__device__ __forceinline__ float sigmoid_fast(float x) {
  return rcp_fast(1.0f + exp2f(x * -1.4426950f));
}

// ---------------------------------------------------------------- pos add
__global__ __launch_bounds__(256) void posadd_kernel(
    const float* __restrict__ emb, const float* __restrict__ pos,
    float* __restrict__ x) {
  int i = blockIdx.x * 256 + threadIdx.x;      // float4 index; total 786432
  const int perB = SEQ * 768 / 4;              // 196608
  int pi = i - (i / perB) * perB;
  float4 e4 = ((const float4*)emb)[i];
  float4 p4 = ((const float4*)pos)[pi];
  e4.x += p4.x; e4.y += p4.y; e4.z += p4.z; e4.w += p4.w;
  ((float4*)x)[i] = e4;
}

// ---------------------------------------------------------------- context mean
__global__ __launch_bounds__(256) void ctxmean_kernel(
    const float* __restrict__ x, float* __restrict__ ctxv) {
  int b = blockIdx.x / 12, chunk = blockIdx.x % 12;
  int lane = threadIdx.x & 63, sg = threadIdx.x >> 6;
  int d = chunk * 64 + lane;
  float acc = 0.f;
  const float* xb = x + ((size_t)b * SEQ + sg) * 768 + d;
  for (int s = sg; s < SEQ; s += 4) { acc += *xb; xb += 4 * 768; }
  __shared__ float red[4][64];
  red[sg][lane] = acc;
  __syncthreads();
  if (threadIdx.x < 64) {
    float t = red[0][threadIdx.x] + red[1][threadIdx.x] +
              red[2][threadIdx.x] + red[3][threadIdx.x];
    ctxv[b * 768 + chunk * 64 + threadIdx.x] = t * (1.0f / 1024.0f);
  }
}

// ---------------------------------------------------------------- small GEMM  C[Mx768] = A[Mx768] @ W[768x768] (+bias)
__global__ __launch_bounds__(256) void gemm768_kernel(
    const float* __restrict__ A, const float* __restrict__ W,
    const float* __restrict__ bias, float* __restrict__ C, int M) {
  __shared__ __align__(16) float sA[16][68];
  __shared__ __align__(16) float sB[16][68];
  const int bm = blockIdx.x * 64;
  const int bn = blockIdx.y * 64;
  const int tid = threadIdx.x;
  const int tm = (tid >> 4) * 4;
  const int tn = (tid & 15) * 4;
  const int lm = tid >> 2, lkq = (tid & 3) * 4;
  const int lkk = tid >> 4, lnq = (tid & 15) * 4;
  float acc[4][4] = {};
  for (int k0 = 0; k0 < 768; k0 += 16) {
    float4 av = make_float4(0.f, 0.f, 0.f, 0.f);
    if (bm + lm < M) av = *(const float4*)&A[(size_t)(bm + lm) * 768 + k0 + lkq];
    float4 wv = *(const float4*)&W[(size_t)(k0 + lkk) * 768 + bn + lnq];
    __syncthreads();
    sA[lkq + 0][lm] = av.x; sA[lkq + 1][lm] = av.y;
    sA[lkq + 2][lm] = av.z; sA[lkq + 3][lm] = av.w;
    *(float4*)&sB[lkk][lnq] = wv;
    __syncthreads();
#pragma unroll
    for (int kk = 0; kk < 16; ++kk) {
      float4 a = *(const float4*)&sA[kk][tm];
      float4 w = *(const float4*)&sB[kk][tn];
      acc[0][0] += a.x * w.x; acc[0][1] += a.x * w.y; acc[0][2] += a.x * w.z; acc[0][3] += a.x * w.w;
      acc[1][0] += a.y * w.x; acc[1][1] += a.y * w.y; acc[1][2] += a.y * w.z; acc[1][3] += a.y * w.w;
      acc[2][0] += a.z * w.x; acc[2][1] += a.z * w.y; acc[2][2] += a.z * w.z; acc[2][3] += a.z * w.w;
      acc[3][0] += a.w * w.x; acc[3][1] += a.w * w.y; acc[3][2] += a.w * w.z; acc[3][3] += a.w * w.w;
    }
  }
#pragma unroll
  for (int i = 0; i < 4; ++i) {
    int row = bm + tm + i;
    if (row < M) {
#pragma unroll
      for (int j = 0; j < 4; ++j) {
        float o = acc[i][j];
        if (bias) o += bias[bn + tn + j];
        C[(size_t)row * 768 + bn + tn + j] = o;
      }
    }
  }
}

// ---------------------------------------------------------------- 4-way fused projection GEMM (shared A, M=512)
struct ProjParams {
  const float* W[4];
  const float* bias[4];
  float* C[4];
};

__global__ __launch_bounds__(256) void gemm768x4_kernel(
    const float* __restrict__ A, ProjParams pp) {
  __shared__ __align__(16) float sA[16][68];
  __shared__ __align__(16) float sB[16][68];
  const int sel = blockIdx.y / 12;
  const float* W = pp.W[sel];
  const float* bias = pp.bias[sel];
  float* C = pp.C[sel];
  const int bm = blockIdx.x * 64;
  const int bn = (blockIdx.y % 12) * 64;
  const int tid = threadIdx.x;
  const int tm = (tid >> 4) * 4;
  const int tn = (tid & 15) * 4;
  const int lm = tid >> 2, lkq = (tid & 3) * 4;
  const int lkk = tid >> 4, lnq = (tid & 15) * 4;
  float acc[4][4] = {};
  for (int k0 = 0; k0 < 768; k0 += 16) {
    float4 av = *(const float4*)&A[(size_t)(bm + lm) * 768 + k0 + lkq];
    float4 wv = *(const float4*)&W[(size_t)(k0 + lkk) * 768 + bn + lnq];
    __syncthreads();
    sA[lkq + 0][lm] = av.x; sA[lkq + 1][lm] = av.y;
    sA[lkq + 2][lm] = av.z; sA[lkq + 3][lm] = av.w;
    *(float4*)&sB[lkk][lnq] = wv;
    __syncthreads();
#pragma unroll
    for (int kk = 0; kk < 16; ++kk) {
      float4 a = *(const float4*)&sA[kk][tm];
      float4 w = *(const float4*)&sB[kk][tn];
      acc[0][0] += a.x * w.x; acc[0][1] += a.x * w.y; acc[0][2] += a.x * w.z; acc[0][3] += a.x * w.w;
      acc[1][0] += a.y * w.x; acc[1][1] += a.y * w.y; acc[1][2] += a.y * w.z; acc[1][3] += a.y * w.w;
      acc[2][0] += a.z * w.x; acc[2][1] += a.z * w.y; acc[2][2] += a.z * w.z; acc[2][3] += a.z * w.w;
      acc[3][0] += a.w * w.x; acc[3][1] += a.w * w.y; acc[3][2] += a.w * w.z; acc[3][3] += a.w * w.w;
    }
  }
#pragma unroll
  for (int i = 0; i < 4; ++i) {
    int row = bm + tm + i;
#pragma unroll
    for (int j = 0; j < 4; ++j) {
      float o = acc[i][j];
      if (bias) o += bias[bn + tn + j];
      C[(size_t)row * 768 + bn + tn + j] = o;
    }
  }
}

// ---------------------------------------------------------------- fused K+V GEMM, 64x128 tile, 4x8 micro, transposed (B,H,S,64) output
__global__ __launch_bounds__(256) void kv_gemm_kernel(
    const float* __restrict__ A,
    const float* __restrict__ Wk, const float* __restrict__ bk,
    const float* __restrict__ Wv, const float* __restrict__ bv,
    float* __restrict__ k2, float* __restrict__ v2) {
  __shared__ __align__(16) float sA[16][68];
  __shared__ __align__(16) float sB[16][132];
  const int bm = blockIdx.x * 64;            // row block of 4096
  const bool isV = blockIdx.y >= 6;
  const int bn = (blockIdx.y % 6) * 128;     // 128-col strip = 2 heads
  const float* W = isV ? Wv : Wk;
  const float* bias = isV ? bv : bk;
  float* out = isV ? v2 : k2;
  const int t = threadIdx.x;
  const int ar = t >> 2, akq = (t & 3) * 4;       // A loader
  const int bkk = t >> 4, bnq = (t & 15) * 8;     // W loader
  const int ty = t >> 4, tx = t & 15;             // 4 rows x (4+4 split cols)

  float acc[4][8] = {};
  for (int k0 = 0; k0 < 768; k0 += 16) {
    float4 av = *(const float4*)&A[(size_t)(bm + ar) * 768 + k0 + akq];
    float4 b0 = *(const float4*)&W[(size_t)(k0 + bkk) * 768 + bn + bnq];
    float4 b1 = *(const float4*)&W[(size_t)(k0 + bkk) * 768 + bn + bnq + 4];
    __syncthreads();
    sA[akq + 0][ar] = av.x; sA[akq + 1][ar] = av.y;
    sA[akq + 2][ar] = av.z; sA[akq + 3][ar] = av.w;
    *(float4*)&sB[bkk][bnq] = b0;
    *(float4*)&sB[bkk][bnq + 4] = b1;
    __syncthreads();
#pragma unroll
    for (int kk = 0; kk < 16; ++kk) {
      float4 a  = *(const float4*)&sA[kk][ty * 4];
      float4 y0 = *(const float4*)&sB[kk][tx * 4];         // head h0 cols
      float4 y1 = *(const float4*)&sB[kk][64 + tx * 4];    // head h0+1 cols
      float xa[4] = {a.x, a.y, a.z, a.w};
      float yb[8] = {y0.x, y0.y, y0.z, y0.w, y1.x, y1.y, y1.z, y1.w};
#pragma unroll
      for (int i = 0; i < 4; ++i)
#pragma unroll
        for (int jj = 0; jj < 8; ++jj)
          acc[i][jj] += xa[i] * yb[jj];
    }
  }

  const int bidx = bm >> 10;
  const int s_base = bm & 1023;
  const int h0 = bn >> 6;
  float bs0[4], bs1[4];
#pragma unroll
  for (int jj = 0; jj < 4; ++jj) {
    bs0[jj] = bias[bn + tx * 4 + jj];
    bs1[jj] = bias[bn + 64 + tx * 4 + jj];
  }
#pragma unroll
  for (int i = 0; i < 4; ++i) {
    int s = s_base + ty * 4 + i;
    float4 o0 = make_float4(acc[i][0] + bs0[0], acc[i][1] + bs0[1],
                            acc[i][2] + bs0[2], acc[i][3] + bs0[3]);
    float4 o1 = make_float4(acc[i][4] + bs1[0], acc[i][5] + bs1[1],
                            acc[i][6] + bs1[2], acc[i][7] + bs1[3]);
    *(float4*)&out[(((size_t)(bidx * 12 + h0)) * 1024 + s) * 64 + tx * 4] = o0;
    *(float4*)&out[(((size_t)(bidx * 12 + h0 + 1)) * 1024 + s) * 64 + tx * 4] = o1;
  }
}

// ---------------------------------------------------------------- flash-style attention, 16 queries/block, (B,H,S,64) K/V
__global__ __launch_bounds__(256) void attn2_kernel(
    const float* __restrict__ q, const float* __restrict__ k2,
    const float* __restrict__ v2, float* __restrict__ ctx,
    float* __restrict__ invsum) {
  __shared__ float p[16][1028];
  __shared__ float4 sK[128 * 16];         // swizzled: [s][dq ^ (s&7)]
  __shared__ float4 sQ[16][16];
  __shared__ float linv[16];
  __shared__ float4 part[4][4][4][16];    // [sq][nq][i][dq]

  const int bid = blockIdx.x;             // 384 = 4 * 12 * 8
  const int b = bid / 96;
  const int rem = bid % 96;
  const int h = rem >> 3;
  const int ng = rem & 7;
  const int t = threadIdx.x;

  {  // stage Q, fold 1/sqrt(64)
    int nn = t >> 4, dq = t & 15;
    float4 qv = *(const float4*)&q[(size_t)(ng * 16 + nn) * 768 + h * 64 + dq * 4];
    qv.x *= 0.125f; qv.y *= 0.125f; qv.z *= 0.125f; qv.w *= 0.125f;
    sQ[nn][dq] = qv;
  }
  const float4* kbh = (const float4*)(k2 + ((size_t)(b * 12 + h)) * 1024 * 64);
  const float4* vbh = (const float4*)(v2 + ((size_t)(b * 12 + h)) * 1024 * 64);

  const int npair = t >> 5;               // 0..7
  const int g = t & 31;
  const int n0 = npair * 2, n1 = n0 + 1;

  // ---- QK^T into p ----
  for (int c = 0; c < 8; ++c) {
    __syncthreads();
#pragma unroll
    for (int w = 0; w < 8; ++w) {
      int fi = w * 256 + t;
      int sl = fi >> 4, dq = fi & 15;
      sK[sl * 16 + (dq ^ (sl & 7))] = kbh[c * 2048 + fi];
    }
    __syncthreads();
    float4 a0[4] = {}, a1[4] = {};
#pragma unroll
    for (int d0 = 0; d0 < 16; ++d0) {
      float4 q0 = sQ[n0][d0];
      float4 q1 = sQ[n1][d0];
      int slot = d0 ^ (g & 7);
#pragma unroll
      for (int u = 0; u < 4; ++u) {
        float4 kv = sK[(g + 32 * u) * 16 + slot];
        a0[u].x += q0.x * kv.x; a0[u].y += q0.y * kv.y;
        a0[u].z += q0.z * kv.z; a0[u].w += q0.w * kv.w;
        a1[u].x += q1.x * kv.x; a1[u].y += q1.y * kv.y;
        a1[u].z += q1.z * kv.z; a1[u].w += q1.w * kv.w;
      }
    }
#pragma unroll
    for (int u = 0; u < 4; ++u) {
      int s = c * 128 + g + 32 * u;
      p[n0][s] = a0[u].x + a0[u].y + a0[u].z + a0[u].w;
      p[n1][s] = a1[u].x + a1[u].y + a1[u].z + a1[u].w;
    }
  }
  __syncthreads();

  // ---- softmax per row; activity = 1/sum ----
  {
    int n = t >> 4, sub = t & 15;
    float m = -1e30f;
#pragma unroll 8
    for (int u = 0; u < 64; ++u) m = fmaxf(m, p[n][sub + 16 * u]);
    m = fmaxf(m, __shfl_xor(m, 1)); m = fmaxf(m, __shfl_xor(m, 2));
    m = fmaxf(m, __shfl_xor(m, 4)); m = fmaxf(m, __shfl_xor(m, 8));
    float sum = 0.f;
#pragma unroll 8
    for (int u = 0; u < 64; ++u) {
      float e = __expf(p[n][sub + 16 * u] - m);
      p[n][sub + 16 * u] = e;
      sum += e;
    }
    sum += __shfl_xor(sum, 1); sum += __shfl_xor(sum, 2);
    sum += __shfl_xor(sum, 4); sum += __shfl_xor(sum, 8);
    if (sub == 0) {
      float inv = 1.0f / sum;
      linv[n] = inv;
      invsum[(b * 12 + h) * 128 + ng * 16 + n] = inv;
    }
  }

  // ---- PV ----
  const int dq = t & 15, nq = (t >> 4) & 3, sq = t >> 6;
  float4 acc[4] = {};
  for (int c = 0; c < 8; ++c) {
    __syncthreads();
#pragma unroll
    for (int w = 0; w < 8; ++w) {
      int fi = w * 256 + t;
      int sl = fi >> 4, dqq = fi & 15;
      sK[sl * 16 + (dqq ^ (sl & 7))] = vbh[c * 2048 + fi];
    }
    __syncthreads();
#pragma unroll 2
    for (int v4 = 0; v4 < 32; v4 += 4) {
      int sl0 = sq * 32 + v4;
      int s0 = c * 128 + sl0;
      float pr[4][4];
#pragma unroll
      for (int i = 0; i < 4; ++i)
        *(float4*)&pr[i][0] = *(const float4*)&p[nq * 4 + i][s0];
#pragma unroll
      for (int u = 0; u < 4; ++u) {
        int sl = sl0 + u;
        float4 vv = sK[sl * 16 + (dq ^ (sl & 7))];
#pragma unroll
        for (int i = 0; i < 4; ++i) {
          float pw = pr[i][u];
          acc[i].x += pw * vv.x; acc[i].y += pw * vv.y;
          acc[i].z += pw * vv.z; acc[i].w += pw * vv.w;
        }
      }
    }
  }
#pragma unroll
  for (int i = 0; i < 4; ++i) part[sq][nq][i][dq] = acc[i];
  __syncthreads();
  {
    int n = t >> 4, dqq = t & 15;
    float4 r0 = part[0][n >> 2][n & 3][dqq];
    float4 r1 = part[1][n >> 2][n & 3][dqq];
    float4 r2 = part[2][n >> 2][n & 3][dqq];
    float4 r3 = part[3][n >> 2][n & 3][dqq];
    float inv = linv[n];
    float4 o;
    o.x = (r0.x + r1.x + r2.x + r3.x) * inv;
    o.y = (r0.y + r1.y + r2.y + r3.y) * inv;
    o.z = (r0.z + r1.z + r2.z + r3.z) * inv;
    o.w = (r0.w + r1.w + r2.w + r3.w) * inv;
    *(float4*)&ctx[(size_t)(b * 128 + ng * 16 + n) * 768 + h * 64 + dqq * 4] = o;
  }
}

// ---------------------------------------------------------------- entity mask
__global__ void mask_kernel(const float* __restrict__ invsum,
                            float* __restrict__ mask_out) {
  int t = threadIdx.x;                   // 512 = B*N
  int b = t >> 7, n = t & 127;
  float a = 0.f;
  for (int h = 0; h < 12; ++h) a = fmaxf(a, invsum[(b * 12 + h) * 128 + n]);
  mask_out[t] = (a > 0.001f) ? 1.0f : 0.0f;
}

// ---------------------------------------------------------------- masked entities out
__global__ __launch_bounds__(256) void entmask_kernel(
    const float* __restrict__ ent, const float* __restrict__ mask,
    float* __restrict__ out) {
  int bi = blockIdx.x;                   // b*128+i
  float m = mask[bi];
  for (int e = threadIdx.x; e < 768; e += 256)
    out[(size_t)bi * 768 + e] = ent[(size_t)bi * 768 + e] * m;
}

// ---------------------------------------------------------------- fused edge refinement + gate + mask
// grid 2048: block = (b, i, j-quarter); 4 waves x 8 j each
__global__ __launch_bounds__(256) void refine_kernel(
    const float* __restrict__ A1, const float* __restrict__ B1,
    const float* __restrict__ C1, const float* __restrict__ w1g,
    const float* __restrict__ W2, const float* __restrict__ b2,
    const float* __restrict__ Ag, const float* __restrict__ Bg,
    const float* __restrict__ Wg2, const float* __restrict__ bg2,
    const float* __restrict__ graph_init, const float* __restrict__ mask,
    float* __restrict__ graph_out) {
  const int bi = blockIdx.x >> 2;        // b*128 + i
  const int jq = blockIdx.x & 3;         // j-quarter
  const int b = bi >> 7;
  const int lane = threadIdx.x & 63, wv = threadIdx.x >> 6;

  float base[12], w1gr[12], w2r[12], agr[12], wg2r[12];
#pragma unroll
  for (int r = 0; r < 12; ++r) {
    int e = r * 64 + lane;
    base[r] = A1[(size_t)bi * 768 + e] + C1[b * 768 + e];
    w1gr[r] = w1g[e];
    w2r[r]  = W2[e];
    agr[r]  = Ag[(size_t)bi * 768 + e];
    wg2r[r] = Wg2[e];
  }
  const float b2s = b2[0], bg2s = bg2[0];
  const float mi = mask[bi];

  const int jend = jq * 32 + 32;
  for (int j = jq * 32 + wv; j < jend; j += 4) {
    float g = graph_init[(size_t)bi * 128 + j] * 1.6f - 0.8f;
    const float* B1j = &B1[((size_t)(b * NE + j)) * 768 + lane];
    const float* Bgj = &Bg[((size_t)(b * NE + j)) * 768 + lane];
    float pre[12], gpre[12];
#pragma unroll
    for (int r = 0; r < 12; ++r) {
      pre[r]  = base[r] + B1j[r * 64];
      gpre[r] = agr[r] + Bgj[r * 64];
    }
#pragma unroll
    for (int st = 0; st < 3; ++st) {
      float acc = 0.f;
#pragma unroll
      for (int r = 0; r < 12; ++r) {
        float hx = pre[r] + g * w1gr[r];
        acc += gelu_fast(hx) * w2r[r];
      }
      acc += __shfl_xor(acc, 1);  acc += __shfl_xor(acc, 2);
      acc += __shfl_xor(acc, 4);  acc += __shfl_xor(acc, 8);
      acc += __shfl_xor(acc, 16); acc += __shfl_xor(acc, 32);
      g += tanh_fast(acc + b2s);
    }
    float gacc = 0.f;
#pragma unroll
    for (int r = 0; r < 12; ++r) gacc += gelu_fast(gpre[r]) * wg2r[r];
    gacc += __shfl_xor(gacc, 1);  gacc += __shfl_xor(gacc, 2);
    gacc += __shfl_xor(gacc, 4);  gacc += __shfl_xor(gacc, 8);
    gacc += __shfl_xor(gacc, 16); gacc += __shfl_xor(gacc, 32);
    float gate = sigmoid_fast(gacc + bg2s);
    if (lane == 0)
      graph_out[(size_t)bi * 128 + j] = g * gate * mi * mask[b * NE + j];
  }
}

}  // namespace

extern "C" void kernel_launch(void* const* d_in, const int* in_sizes, int n_in,
                              void* d_out, int out_size, void* d_ws, size_t ws_size,
                              hipStream_t stream) {
  const float* emb  = (const float*)d_in[0];
  const float* ginit= (const float*)d_in[1];
  const float* lib  = (const float*)d_in[2];
  const float* pos  = (const float*)d_in[3];
  const float* Wq   = (const float*)d_in[4];
  const float* bq   = (const float*)d_in[5];
  const float* Wk   = (const float*)d_in[6];
  const float* bk   = (const float*)d_in[7];
  const float* Wv   = (const float*)d_in[8];
  const float* bv   = (const float*)d_in[9];
  const float* Wo   = (const float*)d_in[10];
  const float* bo   = (const float*)d_in[11];
  const float* W1   = (const float*)d_in[12];
  const float* b1   = (const float*)d_in[13];
  const float* W2   = (const float*)d_in[14];
  const float* b2   = (const float*)d_in[15];
  const float* Wg1  = (const float*)d_in[16];
  const float* bg1  = (const float*)d_in[17];
  const float* Wg2  = (const float*)d_in[18];
  const float* bg2  = (const float*)d_in[19];

  float* ws = (float*)d_ws;
  float* k2   = ws + 0;                 // (B,H,S,64)  3,145,728
  float* v2   = ws + 3145728;           // (B,H,S,64)  3,145,728
  float* x_   = ws + 6291456;           // 3,145,728 (dead after K/V/context)
  float* A1   = ws + 6291456;           // reuse x space
  float* B1   = ws + 6684672;
  float* Ag   = ws + 7077888;
  float* Bg   = ws + 7471104;
  float* q_   = ws + 9437184;           // 98,304
  float* ctx_ = ws + 9535488;           // 393,216
  float* ent_ = ws + 9928704;           // 393,216
  float* ctxv = ws + 10321920;          // 3,072
  float* C1   = ws + 10324992;          // 3,072
  float* invs = ws + 10328064;          // 6,144

  float* out_ent   = (float*)d_out;           // 393,216
  float* out_graph = out_ent + 393216;        // 65,536
  float* out_mask  = out_ent + 458752;        // 512

  // 1. x = emb + pos
  posadd_kernel<<<3072, 256, 0, stream>>>(emb, pos, x_);
  // 2. context = mean_s x
  ctxmean_kernel<<<48, 256, 0, stream>>>(x_, ctxv);
  // 3. q = lib @ Wq + bq
  gemm768_kernel<<<dim3(2, 12), 256, 0, stream>>>(lib, Wq, bq, q_, 128);
  // 4. k2/v2 = x @ Wk/Wv + b, transposed to (B,H,S,64); 768 blocks = 3/CU
  kv_gemm_kernel<<<dim3(64, 12), 256, 0, stream>>>(x_, Wk, bk, Wv, bv, k2, v2);
  // 5. attention -> ctx (B,N,H*K), invsum (B,H,N)
  attn2_kernel<<<384, 256, 0, stream>>>(q_, k2, v2, ctx_, invs);
  // 6. entity mask
  mask_kernel<<<1, 512, 0, stream>>>(invs, out_mask);
  // 7. entities = ctx @ Wo + bo
  gemm768_kernel<<<dim3(8, 12), 256, 0, stream>>>(ctx_, Wo, bo, ent_, 512);
  // 8. masked entities out
  entmask_kernel<<<512, 256, 0, stream>>>(ent_, out_mask, out_ent);
  // 9. fused per-entity projections for edge MLPs (A1,B1,Ag,Bg)
  ProjParams pp;
  pp.W[0] = W1;              pp.bias[0] = nullptr; pp.C[0] = A1;
  pp.W[1] = W1 + 589824;     pp.bias[1] = nullptr; pp.C[1] = B1;
  pp.W[2] = Wg1;             pp.bias[2] = bg1;     pp.C[2] = Ag;
  pp.W[3] = Wg1 + 589824;    pp.bias[3] = nullptr; pp.C[3] = Bg;
  gemm768x4_kernel<<<dim3(8, 48), 256, 0, stream>>>(ent_, pp);
  // 10. C1 = context @ W1d + b1
  gemm768_kernel<<<dim3(1, 12), 256, 0, stream>>>(ctxv, W1 + 1537 * 768, b1, C1, 4);
  // 11. fused edge refinement (3 steps) + gate + entity masking
  refine_kernel<<<2048, 256, 0, stream>>>(A1, B1, C1, W1 + 1536 * 768, W2, b2,
                                          Ag, Bg, Wg2, bg2, ginit, out_mask,
                                          out_graph);
}

// Round 4
// 708.430 us; speedup vs baseline: 1.6466x; 1.0068x over previous
//
#include <hip/hip_runtime.h>
#include <hip/hip_bf16.h>
#include <math.h>

namespace {
constexpr int SEQ  = 1024;
constexpr int NE   = 128;

__device__ __forceinline__ float rcp_fast(float x) {
  return __builtin_amdgcn_rcpf(x);
}

__device__ __forceinline__ float gelu_fast(float x) {
  float x2 = x * x;
  float t = fmaf(x2, -0.1029443f, -2.3022093f);
  return x * rcp_fast(1.0f + exp2f(x * t));
}

__device__ __forceinline__ float tanh_fast(float x) {
  return 1.0f - 2.0f * rcp_fast(1.0f + exp2f(x * 2.8853901f));
}

__device__ __forceinline__ float sigmoid_fast(float x) {
  return rcp_fast(1.0f + exp2f(x * -1.4426950f));
}

__device__ __forceinline__ void atomAddF(float* p, float v) {
  unsafeAtomicAdd(p, v);   // hw global_atomic_add_f32
}

// ---------------------------------------------------------------- zero
__global__ __launch_bounds__(256) void zero_kernel(float4* __restrict__ p) {
  p[(size_t)blockIdx.x * 256 + threadIdx.x] = make_float4(0.f, 0.f, 0.f, 0.f);
}

// ---------------------------------------------------------------- pos add
__global__ __launch_bounds__(256) void posadd_kernel(
    const float* __restrict__ emb, const float* __restrict__ pos,
    float* __restrict__ x) {
  int i = blockIdx.x * 256 + threadIdx.x;      // float4 index; total 786432
  const int perB = SEQ * 768 / 4;              // 196608
  int pi = i - (i / perB) * perB;
  float4 e4 = ((const float4*)emb)[i];
  float4 p4 = ((const float4*)pos)[pi];
  e4.x += p4.x; e4.y += p4.y; e4.z += p4.z; e4.w += p4.w;
  ((float4*)x)[i] = e4;
}

// ---------------------------------------------------------------- context mean
__global__ __launch_bounds__(1024) void ctxmean_kernel(
    const float* __restrict__ x, float* __restrict__ ctxv) {
  int b = blockIdx.x / 12, chunk = blockIdx.x % 12;
  int lane = threadIdx.x & 63, sg = threadIdx.x >> 6;   // sg 0..15
  int d = chunk * 64 + lane;
  float acc = 0.f;
  const float* xb = x + ((size_t)b * SEQ + sg) * 768 + d;
  for (int s = sg; s < SEQ; s += 16) { acc += *xb; xb += 16 * 768; }
  __shared__ float red[16][64];
  red[sg][lane] = acc;
  __syncthreads();
  if (threadIdx.x < 64) {
    float t = 0.f;
#pragma unroll
    for (int r = 0; r < 16; ++r) t += red[r][threadIdx.x];
    ctxv[b * 768 + chunk * 64 + threadIdx.x] = t * (1.0f / 1024.0f);
  }
}

// ---------------------------------------------------------------- legacy small GEMM (kept for C1, M=4)
__global__ __launch_bounds__(256) void gemm768_kernel(
    const float* __restrict__ A, const float* __restrict__ W,
    const float* __restrict__ bias, float* __restrict__ C, int M) {
  __shared__ __align__(16) float sA[16][68];
  __shared__ __align__(16) float sB[16][68];
  const int bm = blockIdx.x * 64;
  const int bn = blockIdx.y * 64;
  const int tid = threadIdx.x;
  const int tm = (tid >> 4) * 4;
  const int tn = (tid & 15) * 4;
  const int lm = tid >> 2, lkq = (tid & 3) * 4;
  const int lkk = tid >> 4, lnq = (tid & 15) * 4;
  float acc[4][4] = {};
  for (int k0 = 0; k0 < 768; k0 += 16) {
    float4 av = make_float4(0.f, 0.f, 0.f, 0.f);
    if (bm + lm < M) av = *(const float4*)&A[(size_t)(bm + lm) * 768 + k0 + lkq];
    float4 wv = *(const float4*)&W[(size_t)(k0 + lkk) * 768 + bn + lnq];
    __syncthreads();
    sA[lkq + 0][lm] = av.x; sA[lkq + 1][lm] = av.y;
    sA[lkq + 2][lm] = av.z; sA[lkq + 3][lm] = av.w;
    *(float4*)&sB[lkk][lnq] = wv;
    __syncthreads();
#pragma unroll
    for (int kk = 0; kk < 16; ++kk) {
      float4 a = *(const float4*)&sA[kk][tm];
      float4 w = *(const float4*)&sB[kk][tn];
      acc[0][0] += a.x * w.x; acc[0][1] += a.x * w.y; acc[0][2] += a.x * w.z; acc[0][3] += a.x * w.w;
      acc[1][0] += a.y * w.x; acc[1][1] += a.y * w.y; acc[1][2] += a.y * w.z; acc[1][3] += a.y * w.w;
      acc[2][0] += a.z * w.x; acc[2][1] += a.z * w.y; acc[2][2] += a.z * w.z; acc[2][3] += a.z * w.w;
      acc[3][0] += a.w * w.x; acc[3][1] += a.w * w.y; acc[3][2] += a.w * w.z; acc[3][3] += a.w * w.w;
    }
  }
#pragma unroll
  for (int i = 0; i < 4; ++i) {
    int row = bm + tm + i;
    if (row < M) {
#pragma unroll
      for (int j = 0; j < 4; ++j) {
        float o = acc[i][j];
        if (bias) o += bias[bn + tn + j];
        C[(size_t)row * 768 + bn + tn + j] = o;
      }
    }
  }
}

// ---------------------------------------------------------------- split-K GEMM, 64x128 tile, 8x(4+4) micro, 128 threads
// C[sel] += A[64-rows x K-slice] @ W[sel]; grid (M/64, 6, nmat*ks)
struct GemmSet {
  const float* W[4];
  const float* bias[4];
  float* C[4];
};

__global__ __launch_bounds__(128) void gemm_splitk_kernel(
    const float* __restrict__ A, GemmSet gs, int ks, int KB) {
  __shared__ __align__(16) float sA[16][68];
  __shared__ __align__(16) float sB[16][132];
  const int sel = blockIdx.z / ks;
  const int kb  = blockIdx.z % ks;
  const float* __restrict__ W = gs.W[sel];
  const float* __restrict__ bias = gs.bias[sel];
  float* __restrict__ C = gs.C[sel];
  const int bm = blockIdx.x * 64;
  const int bn = blockIdx.y * 128;
  const int t = threadIdx.x;
  const int ar = t >> 1, akq = (t & 1) * 8;       // A loader: 2 float4
  const int bkr = t >> 3, bc = (t & 7) * 16;      // W loader: 4 float4
  const int ty = t >> 4, tx = t & 15;             // 8 rows x (4+4) cols
  const int kbeg = kb * KB, kend = kbeg + KB;

  const float* __restrict__ Ap = A + (size_t)(bm + ar) * 768 + akq;
  const float* __restrict__ Wp = W + (size_t)bkr * 768 + bn + bc;

  float4 a0 = *(const float4*)(Ap + kbeg);
  float4 a1 = *(const float4*)(Ap + kbeg + 4);
  const float* wr0 = Wp + (size_t)kbeg * 768;
  float4 w0 = *(const float4*)(wr0);
  float4 w1 = *(const float4*)(wr0 + 4);
  float4 w2 = *(const float4*)(wr0 + 8);
  float4 w3 = *(const float4*)(wr0 + 12);

  float acc[8][8] = {};
  for (int k0 = kbeg; k0 < kend; k0 += 16) {
    __syncthreads();
    sA[akq + 0][ar] = a0.x; sA[akq + 1][ar] = a0.y;
    sA[akq + 2][ar] = a0.z; sA[akq + 3][ar] = a0.w;
    sA[akq + 4][ar] = a1.x; sA[akq + 5][ar] = a1.y;
    sA[akq + 6][ar] = a1.z; sA[akq + 7][ar] = a1.w;
    *(float4*)&sB[bkr][bc]      = w0;
    *(float4*)&sB[bkr][bc + 4]  = w1;
    *(float4*)&sB[bkr][bc + 8]  = w2;
    *(float4*)&sB[bkr][bc + 12] = w3;
    __syncthreads();
    if (k0 + 16 < kend) {      // prefetch next slice; overlaps compute
      a0 = *(const float4*)(Ap + k0 + 16);
      a1 = *(const float4*)(Ap + k0 + 20);
      const float* wr = Wp + (size_t)(k0 + 16) * 768;
      w0 = *(const float4*)(wr);
      w1 = *(const float4*)(wr + 4);
      w2 = *(const float4*)(wr + 8);
      w3 = *(const float4*)(wr + 12);
    }
#pragma unroll
    for (int kk = 0; kk < 16; ++kk) {
      float4 x0 = *(const float4*)&sA[kk][ty * 8];
      float4 x1 = *(const float4*)&sA[kk][ty * 8 + 4];
      float4 y0 = *(const float4*)&sB[kk][tx * 4];
      float4 y1 = *(const float4*)&sB[kk][64 + tx * 4];
      float xa[8] = {x0.x, x0.y, x0.z, x0.w, x1.x, x1.y, x1.z, x1.w};
      float yb[8] = {y0.x, y0.y, y0.z, y0.w, y1.x, y1.y, y1.z, y1.w};
#pragma unroll
      for (int i = 0; i < 8; ++i)
#pragma unroll
        for (int j = 0; j < 8; ++j)
          acc[i][j] += xa[i] * yb[j];
    }
  }

  float b0a[4], b1a[4];
  const bool addb = (kb == 0) && (bias != nullptr);
#pragma unroll
  for (int j = 0; j < 4; ++j) {
    b0a[j] = addb ? bias[bn + tx * 4 + j] : 0.0f;
    b1a[j] = addb ? bias[bn + 64 + tx * 4 + j] : 0.0f;
  }
#pragma unroll
  for (int i = 0; i < 8; ++i) {
    float* crow = C + (size_t)(bm + ty * 8 + i) * 768;
#pragma unroll
    for (int j = 0; j < 4; ++j) {
      atomAddF(crow + bn + tx * 4 + j,      acc[i][j]     + b0a[j]);
      atomAddF(crow + bn + 64 + tx * 4 + j, acc[i][4 + j] + b1a[j]);
    }
  }
}

// ---------------------------------------------------------------- fused K+V GEMM, 64x128 tile, 8x(4+4) micro, 128 threads
// output transposed to (B,H,S,64)
__global__ __launch_bounds__(128) void kv_gemm_kernel(
    const float* __restrict__ A,
    const float* __restrict__ Wk, const float* __restrict__ bk,
    const float* __restrict__ Wv, const float* __restrict__ bv,
    float* __restrict__ k2, float* __restrict__ v2) {
  __shared__ __align__(16) float sA[16][68];
  __shared__ __align__(16) float sB[16][132];
  const int bm = blockIdx.x * 64;
  const bool isV = blockIdx.y >= 6;
  const int bn = (blockIdx.y % 6) * 128;     // 2 heads
  const float* __restrict__ W = isV ? Wv : Wk;
  const float* __restrict__ bias = isV ? bv : bk;
  float* __restrict__ out = isV ? v2 : k2;
  const int t = threadIdx.x;
  const int ar = t >> 1, akq = (t & 1) * 8;
  const int bkr = t >> 3, bc = (t & 7) * 16;
  const int ty = t >> 4, tx = t & 15;

  const float* __restrict__ Ap = A + (size_t)(bm + ar) * 768 + akq;
  const float* __restrict__ Wp = W + (size_t)bkr * 768 + bn + bc;

  float4 a0 = *(const float4*)(Ap);
  float4 a1 = *(const float4*)(Ap + 4);
  float4 w0 = *(const float4*)(Wp);
  float4 w1 = *(const float4*)(Wp + 4);
  float4 w2 = *(const float4*)(Wp + 8);
  float4 w3 = *(const float4*)(Wp + 12);

  float acc[8][8] = {};
  for (int k0 = 0; k0 < 768; k0 += 16) {
    __syncthreads();
    sA[akq + 0][ar] = a0.x; sA[akq + 1][ar] = a0.y;
    sA[akq + 2][ar] = a0.z; sA[akq + 3][ar] = a0.w;
    sA[akq + 4][ar] = a1.x; sA[akq + 5][ar] = a1.y;
    sA[akq + 6][ar] = a1.z; sA[akq + 7][ar] = a1.w;
    *(float4*)&sB[bkr][bc]      = w0;
    *(float4*)&sB[bkr][bc + 4]  = w1;
    *(float4*)&sB[bkr][bc + 8]  = w2;
    *(float4*)&sB[bkr][bc + 12] = w3;
    __syncthreads();
    if (k0 + 16 < 768) {
      a0 = *(const float4*)(Ap + k0 + 16);
      a1 = *(const float4*)(Ap + k0 + 20);
      const float* wr = Wp + (size_t)(k0 + 16) * 768;
      w0 = *(const float4*)(wr);
      w1 = *(const float4*)(wr + 4);
      w2 = *(const float4*)(wr + 8);
      w3 = *(const float4*)(wr + 12);
    }
#pragma unroll
    for (int kk = 0; kk < 16; ++kk) {
      float4 x0 = *(const float4*)&sA[kk][ty * 8];
      float4 x1 = *(const float4*)&sA[kk][ty * 8 + 4];
      float4 y0 = *(const float4*)&sB[kk][tx * 4];
      float4 y1 = *(const float4*)&sB[kk][64 + tx * 4];
      float xa[8] = {x0.x, x0.y, x0.z, x0.w, x1.x, x1.y, x1.z, x1.w};
      float yb[8] = {y0.x, y0.y, y0.z, y0.w, y1.x, y1.y, y1.z, y1.w};
#pragma unroll
      for (int i = 0; i < 8; ++i)
#pragma unroll
        for (int j = 0; j < 8; ++j)
          acc[i][j] += xa[i] * yb[j];
    }
  }

  const int bidx = bm >> 10;
  const int s_base = bm & 1023;
  const int h0 = bn >> 6;
  float bs0[4], bs1[4];
#pragma unroll
  for (int j = 0; j < 4; ++j) {
    bs0[j] = bias[bn + tx * 4 + j];
    bs1[j] = bias[bn + 64 + tx * 4 + j];
  }
#pragma unroll
  for (int i = 0; i < 8; ++i) {
    int s = s_base + ty * 8 + i;
    float4 o0 = make_float4(acc[i][0] + bs0[0], acc[i][1] + bs0[1],
                            acc[i][2] + bs0[2], acc[i][3] + bs0[3]);
    float4 o1 = make_float4(acc[i][4] + bs1[0], acc[i][5] + bs1[1],
                            acc[i][6] + bs1[2], acc[i][7] + bs1[3]);
    *(float4*)&out[(((size_t)(bidx * 12 + h0)) * 1024 + s) * 64 + tx * 4] = o0;
    *(float4*)&out[(((size_t)(bidx * 12 + h0 + 1)) * 1024 + s) * 64 + tx * 4] = o1;
  }
}

// ---------------------------------------------------------------- flash-style attention, 16 queries/block, (B,H,S,64) K/V
// blockIdx remapped so the 8 q-groups of one (b,h) land on one XCD (L2 reuse)
__global__ __launch_bounds__(256) void attn2_kernel(
    const float* __restrict__ q, const float* __restrict__ k2,
    const float* __restrict__ v2, float* __restrict__ ctx,
    float* __restrict__ invsum) {
  __shared__ float p[16][1028];
  __shared__ float4 sK[128 * 16];         // swizzled: [s][dq ^ (s&7)]
  __shared__ float4 sQ[16][16];
  __shared__ float linv[16];
  __shared__ float4 part[4][4][4][16];    // [sq][nq][i][dq]

  // XCD-aware remap: consecutive blockIdx round-robin XCDs; keep one bh per XCD chunk
  const int xcd = blockIdx.x & 7;
  const int slot = blockIdx.x >> 3;       // 0..47
  const int bh = xcd * 6 + (slot >> 3);   // 0..47
  const int ng = slot & 7;
  const int b = bh / 12, h = bh % 12;
  const int t = threadIdx.x;

  {  // stage Q, fold 1/sqrt(64)
    int nn = t >> 4, dq = t & 15;
    float4 qv = *(const float4*)&q[(size_t)(ng * 16 + nn) * 768 + h * 64 + dq * 4];
    qv.x *= 0.125f; qv.y *= 0.125f; qv.z *= 0.125f; qv.w *= 0.125f;
    sQ[nn][dq] = qv;
  }
  const float4* kbh = (const float4*)(k2 + ((size_t)(b * 12 + h)) * 1024 * 64);
  const float4* vbh = (const float4*)(v2 + ((size_t)(b * 12 + h)) * 1024 * 64);

  const int npair = t >> 5;               // 0..7
  const int g = t & 31;
  const int n0 = npair * 2, n1 = n0 + 1;

  // ---- QK^T into p ----
  for (int c = 0; c < 8; ++c) {
    __syncthreads();
#pragma unroll
    for (int w = 0; w < 8; ++w) {
      int fi = w * 256 + t;
      int sl = fi >> 4, dq = fi & 15;
      sK[sl * 16 + (dq ^ (sl & 7))] = kbh[c * 2048 + fi];
    }
    __syncthreads();
    float4 a0[4] = {}, a1[4] = {};
#pragma unroll
    for (int d0 = 0; d0 < 16; ++d0) {
      float4 q0 = sQ[n0][d0];
      float4 q1 = sQ[n1][d0];
      int slot2 = d0 ^ (g & 7);
#pragma unroll
      for (int u = 0; u < 4; ++u) {
        float4 kv = sK[(g + 32 * u) * 16 + slot2];
        a0[u].x += q0.x * kv.x; a0[u].y += q0.y * kv.y;
        a0[u].z += q0.z * kv.z; a0[u].w += q0.w * kv.w;
        a1[u].x += q1.x * kv.x; a1[u].y += q1.y * kv.y;
        a1[u].z += q1.z * kv.z; a1[u].w += q1.w * kv.w;
      }
    }
#pragma unroll
    for (int u = 0; u < 4; ++u) {
      int s = c * 128 + g + 32 * u;
      p[n0][s] = a0[u].x + a0[u].y + a0[u].z + a0[u].w;
      p[n1][s] = a1[u].x + a1[u].y + a1[u].z + a1[u].w;
    }
  }
  __syncthreads();

  // ---- softmax per row; activity = 1/sum ----
  {
    int n = t >> 4, sub = t & 15;
    float m = -1e30f;
#pragma unroll 8
    for (int u = 0; u < 64; ++u) m = fmaxf(m, p[n][sub + 16 * u]);
    m = fmaxf(m, __shfl_xor(m, 1)); m = fmaxf(m, __shfl_xor(m, 2));
    m = fmaxf(m, __shfl_xor(m, 4)); m = fmaxf(m, __shfl_xor(m, 8));
    float sum = 0.f;
#pragma unroll 8
    for (int u = 0; u < 64; ++u) {
      float e = __expf(p[n][sub + 16 * u] - m);
      p[n][sub + 16 * u] = e;
      sum += e;
    }
    sum += __shfl_xor(sum, 1); sum += __shfl_xor(sum, 2);
    sum += __shfl_xor(sum, 4); sum += __shfl_xor(sum, 8);
    if (sub == 0) {
      float inv = 1.0f / sum;
      linv[n] = inv;
      invsum[(b * 12 + h) * 128 + ng * 16 + n] = inv;
    }
  }

  // ---- PV ----
  const int dq = t & 15, nq = (t >> 4) & 3, sq = t >> 6;
  float4 acc[4] = {};
  for (int c = 0; c < 8; ++c) {
    __syncthreads();
#pragma unroll
    for (int w = 0; w < 8; ++w) {
      int fi = w * 256 + t;
      int sl = fi >> 4, dqq = fi & 15;
      sK[sl * 16 + (dqq ^ (sl & 7))] = vbh[c * 2048 + fi];
    }
    __syncthreads();
#pragma unroll 2
    for (int v4 = 0; v4 < 32; v4 += 4) {
      int sl0 = sq * 32 + v4;
      int s0 = c * 128 + sl0;
      float pr[4][4];
#pragma unroll
      for (int i = 0; i < 4; ++i)
        *(float4*)&pr[i][0] = *(const float4*)&p[nq * 4 + i][s0];
#pragma unroll
      for (int u = 0; u < 4; ++u) {
        int sl = sl0 + u;
        float4 vv = sK[sl * 16 + (dq ^ (sl & 7))];
#pragma unroll
        for (int i = 0; i < 4; ++i) {
          float pw = pr[i][u];
          acc[i].x += pw * vv.x; acc[i].y += pw * vv.y;
          acc[i].z += pw * vv.z; acc[i].w += pw * vv.w;
        }
      }
    }
  }
#pragma unroll
  for (int i = 0; i < 4; ++i) part[sq][nq][i][dq] = acc[i];
  __syncthreads();
  {
    int n = t >> 4, dqq = t & 15;
    float4 r0 = part[0][n >> 2][n & 3][dqq];
    float4 r1 = part[1][n >> 2][n & 3][dqq];
    float4 r2 = part[2][n >> 2][n & 3][dqq];
    float4 r3 = part[3][n >> 2][n & 3][dqq];
    float inv = linv[n];
    float4 o;
    o.x = (r0.x + r1.x + r2.x + r3.x) * inv;
    o.y = (r0.y + r1.y + r2.y + r3.y) * inv;
    o.z = (r0.z + r1.z + r2.z + r3.z) * inv;
    o.w = (r0.w + r1.w + r2.w + r3.w) * inv;
    *(float4*)&ctx[(size_t)(b * 128 + ng * 16 + n) * 768 + h * 64 + dqq * 4] = o;
  }
}

// ---------------------------------------------------------------- entity mask
__global__ void mask_kernel(const float* __restrict__ invsum,
                            float* __restrict__ mask_out) {
  int t = threadIdx.x;                   // 512 = B*N
  int b = t >> 7, n = t & 127;
  float a = 0.f;
  for (int h = 0; h < 12; ++h) a = fmaxf(a, invsum[(b * 12 + h) * 128 + n]);
  mask_out[t] = (a > 0.001f) ? 1.0f : 0.0f;
}

// ---------------------------------------------------------------- masked entities out
__global__ __launch_bounds__(256) void entmask_kernel(
    const float* __restrict__ ent, const float* __restrict__ mask,
    float* __restrict__ out) {
  int bi = blockIdx.x;                   // b*128+i
  float m = mask[bi];
  for (int e = threadIdx.x; e < 768; e += 256)
    out[(size_t)bi * 768 + e] = ent[(size_t)bi * 768 + e] * m;
}

// ---------------------------------------------------------------- fused edge refinement + gate + mask
__global__ __launch_bounds__(256) void refine_kernel(
    const float* __restrict__ A1, const float* __restrict__ B1,
    const float* __restrict__ C1, const float* __restrict__ w1g,
    const float* __restrict__ W2, const float* __restrict__ b2,
    const float* __restrict__ Ag, const float* __restrict__ Bg,
    const float* __restrict__ Wg2, const float* __restrict__ bg2,
    const float* __restrict__ graph_init, const float* __restrict__ mask,
    float* __restrict__ graph_out) {
  const int bi = blockIdx.x >> 2;        // b*128 + i
  const int jq = blockIdx.x & 3;         // j-quarter
  const int b = bi >> 7;
  const int lane = threadIdx.x & 63, wv = threadIdx.x >> 6;

  float base[12], w1gr[12], w2r[12], agr[12], wg2r[12];
#pragma unroll
  for (int r = 0; r < 12; ++r) {
    int e = r * 64 + lane;
    base[r] = A1[(size_t)bi * 768 + e] + C1[b * 768 + e];
    w1gr[r] = w1g[e];
    w2r[r]  = W2[e];
    agr[r]  = Ag[(size_t)bi * 768 + e];
    wg2r[r] = Wg2[e];
  }
  const float b2s = b2[0], bg2s = bg2[0];
  const float mi = mask[bi];

  const int jend = jq * 32 + 32;
  for (int j = jq * 32 + wv; j < jend; j += 4) {
    float g = graph_init[(size_t)bi * 128 + j] * 1.6f - 0.8f;
    const float* B1j = &B1[((size_t)(b * NE + j)) * 768 + lane];
    const float* Bgj = &Bg[((size_t)(b * NE + j)) * 768 + lane];
    float pre[12], gpre[12];
#pragma unroll
    for (int r = 0; r < 12; ++r) {
      pre[r]  = base[r] + B1j[r * 64];
      gpre[r] = agr[r] + Bgj[r * 64];
    }
#pragma unroll
    for (int st = 0; st < 3; ++st) {
      float acc = 0.f;
#pragma unroll
      for (int r = 0; r < 12; ++r) {
        float hx = pre[r] + g * w1gr[r];
        acc += gelu_fast(hx) * w2r[r];
      }
      acc += __shfl_xor(acc, 1);  acc += __shfl_xor(acc, 2);
      acc += __shfl_xor(acc, 4);  acc += __shfl_xor(acc, 8);
      acc += __shfl_xor(acc, 16); acc += __shfl_xor(acc, 32);
      g += tanh_fast(acc + b2s);
    }
    float gacc = 0.f;
#pragma unroll
    for (int r = 0; r < 12; ++r) gacc += gelu_fast(gpre[r]) * wg2r[r];
    gacc += __shfl_xor(gacc, 1);  gacc += __shfl_xor(gacc, 2);
    gacc += __shfl_xor(gacc, 4);  gacc += __shfl_xor(gacc, 8);
    gacc += __shfl_xor(gacc, 16); gacc += __shfl_xor(gacc, 32);
    float gate = sigmoid_fast(gacc + bg2s);
    if (lane == 0)
      graph_out[(size_t)bi * 128 + j] = g * gate * mi * mask[b * NE + j];
  }
}

}  // namespace

extern "C" void kernel_launch(void* const* d_in, const int* in_sizes, int n_in,
                              void* d_out, int out_size, void* d_ws, size_t ws_size,
                              hipStream_t stream) {
  const float* emb  = (const float*)d_in[0];
  const float* ginit= (const float*)d_in[1];
  const float* lib  = (const float*)d_in[2];
  const float* pos  = (const float*)d_in[3];
  const float* Wq   = (const float*)d_in[4];
  const float* bq   = (const float*)d_in[5];
  const float* Wk   = (const float*)d_in[6];
  const float* bk   = (const float*)d_in[7];
  const float* Wv   = (const float*)d_in[8];
  const float* bv   = (const float*)d_in[9];
  const float* Wo   = (const float*)d_in[10];
  const float* bo   = (const float*)d_in[11];
  const float* W1   = (const float*)d_in[12];
  const float* b1   = (const float*)d_in[13];
  const float* W2   = (const float*)d_in[14];
  const float* b2   = (const float*)d_in[15];
  const float* Wg1  = (const float*)d_in[16];
  const float* bg1  = (const float*)d_in[17];
  const float* Wg2  = (const float*)d_in[18];
  const float* bg2  = (const float*)d_in[19];

  float* ws = (float*)d_ws;
  float* k2   = ws + 0;                 // (B,H,S,64)  3,145,728
  float* v2   = ws + 3145728;           // (B,H,S,64)  3,145,728
  float* x_   = ws + 6291456;           // 3,145,728 (dead after kv_gemm)
  float* A1   = ws + 6291456;           // reuse x space (zeroed after kv)
  float* B1   = ws + 6684672;
  float* Ag   = ws + 7077888;
  float* Bg   = ws + 7471104;           // ends 7864320
  float* q_   = ws + 9437184;           // 98,304
  float* ctx_ = ws + 9535488;           // 393,216
  float* ent_ = ws + 9928704;           // 393,216
  float* ctxv = ws + 10321920;          // 3,072
  float* C1   = ws + 10324992;          // 3,072
  float* invs = ws + 10328064;          // 6,144

  float* out_ent   = (float*)d_out;           // 393,216
  float* out_graph = out_ent + 393216;        // 65,536
  float* out_mask  = out_ent + 458752;        // 512

  // 0. zero accumulation targets q_, ctx_, ent_ (contiguous 884736 floats)
  zero_kernel<<<864, 256, 0, stream>>>((float4*)q_);
  // 1. x = emb + pos
  posadd_kernel<<<3072, 256, 0, stream>>>(emb, pos, x_);
  // 2. context = mean_s x
  ctxmean_kernel<<<48, 1024, 0, stream>>>(x_, ctxv);
  // 3. q = lib @ Wq + bq (split-K x8)
  {
    GemmSet gq; gq.W[0] = Wq; gq.bias[0] = bq; gq.C[0] = q_;
    gemm_splitk_kernel<<<dim3(2, 6, 8), 128, 0, stream>>>(lib, gq, 8, 96);
  }
  // 4. k2/v2 = x @ Wk/Wv + b, transposed to (B,H,S,64)
  kv_gemm_kernel<<<dim3(64, 12), 128, 0, stream>>>(x_, Wk, bk, Wv, bv, k2, v2);
  // 5. attention -> ctx (B,N,H*K), invsum (B,H,N)
  attn2_kernel<<<384, 256, 0, stream>>>(q_, k2, v2, ctx_, invs);
  // 6. entity mask
  mask_kernel<<<1, 512, 0, stream>>>(invs, out_mask);
  // 7. entities = ctx @ Wo + bo (split-K x8)
  {
    GemmSet go; go.W[0] = Wo; go.bias[0] = bo; go.C[0] = ent_;
    gemm_splitk_kernel<<<dim3(8, 6, 8), 128, 0, stream>>>(ctx_, go, 8, 96);
  }
  // 8. masked entities out
  entmask_kernel<<<512, 256, 0, stream>>>(ent_, out_mask, out_ent);
  // 9. zero A1..Bg (x_ now dead), then fused projections (split-K x4, 4 mats)
  zero_kernel<<<1536, 256, 0, stream>>>((float4*)A1);
  {
    GemmSet gp;
    gp.W[0] = W1;           gp.bias[0] = nullptr; gp.C[0] = A1;
    gp.W[1] = W1 + 589824;  gp.bias[1] = nullptr; gp.C[1] = B1;
    gp.W[2] = Wg1;          gp.bias[2] = bg1;     gp.C[2] = Ag;
    gp.W[3] = Wg1 + 589824; gp.bias[3] = nullptr; gp.C[3] = Bg;
    gemm_splitk_kernel<<<dim3(8, 6, 16), 128, 0, stream>>>(ent_, gp, 4, 192);
  }
  // 10. C1 = context @ W1d + b1
  gemm768_kernel<<<dim3(1, 12), 256, 0, stream>>>(ctxv, W1 + 1537 * 768, b1, C1, 4);
  // 11. fused edge refinement (3 steps) + gate + entity masking
  refine_kernel<<<2048, 256, 0, stream>>>(A1, B1, C1, W1 + 1536 * 768, W2, b2,
                                          Ag, Bg, Wg2, bg2, ginit, out_mask,
                                          out_graph);
}